// Round 6
// baseline (309.217 us; speedup 1.0000x reference)
//
#include <hip/hip_runtime.h>
#include <hip/hip_cooperative_groups.h>
#include <cstdint>
#include <cmath>

namespace cg = cooperative_groups;

#define NB 16
#define AANCH 16320
#define NCLS 80
#define KPRE 1000
#define MAXDET 300
#define NCH 16            // 16 chunks of 64 >= 1000 candidates
#define CCAP 4096
#define HBINS 8192
#define GRID 256
#define BLK 1024

// logit(0.05)
#define THR_LOGIT -2.9444389791664403f

__global__ __launch_bounds__(BLK, 1) void mega(
    const float* __restrict__ cls, const float* __restrict__ boxp,
    const float* __restrict__ anchors, float* __restrict__ out,
    uint32_t* __restrict__ key, int* __restrict__ label,
    uint32_t* __restrict__ candKey, uint32_t* __restrict__ candIdx,
    uint32_t* __restrict__ candCount, uint32_t* __restrict__ validCnt,
    float4* __restrict__ topBox, float* __restrict__ topScore,
    int* __restrict__ topLabel, unsigned long long* __restrict__ maskT) {
    cg::grid_group gg = cg::this_grid();
    // ~87 KB static LDS: forces exactly 1 block/CU -> 256 blocks spread over 256 CUs
    __shared__ uint32_t hist[HBINS];             // 32 KB (P2)
    __shared__ unsigned long long tp[CCAP];      // 32 KB (P3)
    __shared__ float4 cobS[16][64];              // 16 KB (P4)
    __shared__ float  carS[16][64];              //  4 KB (P4)
    __shared__ uint32_t part[256];
    __shared__ uint32_t s_pivot, s_pos;
    int tid = threadIdx.x;
    int bx = blockIdx.x;

    // ================= P1: score (streaming max/argmax, 4 lanes/anchor) =================
    {
        int T = bx * BLK + tid;
#pragma unroll
        for (int it = 0; it < 4; ++it) {
            int idx4 = it * (GRID * BLK) + T;
            int am = idx4 >> 2, g = idx4 & 3;     // g == T&3: 4-lane groups lane-aligned
            bool act = am < NB * AANCH;
            float best = -3e38f; int bi = 0;
            if (act) {
                const float4* p = (const float4*)(cls + (size_t)am * NCLS) + g;
#pragma unroll
                for (int i = 0; i < 5; ++i) {
                    float4 v = p[4 * i];
                    int c0 = 4 * g + 16 * i;
                    if (v.x > best) { best = v.x; bi = c0 + 0; }
                    if (v.y > best) { best = v.y; bi = c0 + 1; }
                    if (v.z > best) { best = v.z; bi = c0 + 2; }
                    if (v.w > best) { best = v.w; bi = c0 + 3; }
                }
            }
#pragma unroll
            for (int m = 1; m <= 2; m <<= 1) {    // reduce 4-lane group, lowest class wins ties
                float ob = __shfl_xor(best, m, 64);
                int oi = __shfl_xor(bi, m, 64);
                if (ob > best || (ob == best && oi < bi)) { best = ob; bi = oi; }
            }
            if (act && g == 0) {
                uint32_t k = 0;
                if (best > THR_LOGIT) {
                    uint32_t ub = __float_as_uint(best);
                    k = (ub & 0x80000000u) ? ~ub : (ub | 0x80000000u);
                }
                key[am] = k;
                label[am] = bi;
            }
        }
    }
    gg.sync();

    // ================= P2: per-image hist + pivot + compaction (blocks 0..15) =================
    if (bx < NB) {
        int b = bx;
        for (int i = tid; i < HBINS; i += BLK) hist[i] = 0;
        if (tid == 0) s_pos = 0;
        __syncthreads();
        const uint32_t* kb = key + (size_t)b * AANCH;
        for (int i = tid; i < AANCH; i += BLK) atomicAdd(&hist[kb[i] >> 19], 1u);
        __syncthreads();
        if (tid < 256) {
            uint32_t s = 0;
#pragma unroll
            for (int i = 0; i < 32; ++i) s += hist[tid * 32 + ((i + tid) & 31)];
            part[tid] = s;
        }
        __syncthreads();
        if (tid == 0) {
            uint32_t acc = 0; int tc = 0;
            for (int t2 = 255; t2 >= 0; --t2) {
                if (acc + part[t2] >= (uint32_t)KPRE) { tc = t2; break; }
                acc += part[t2];
            }
            uint32_t p1 = 0;
            for (int bin = tc * 32 + 31; bin >= tc * 32; --bin) {
                if (acc + hist[bin] >= (uint32_t)KPRE) { p1 = (uint32_t)bin; break; }
                acc += hist[bin];
            }
            s_pivot = p1;
            uint32_t nvalid = (uint32_t)AANCH - hist[0];  // bin 0 == key==0 entries exactly
            validCnt[b] = nvalid < (uint32_t)KPRE ? nvalid : (uint32_t)KPRE;
        }
        __syncthreads();
        uint32_t piv = s_pivot;
        for (int i = tid; i < AANCH; i += BLK) {
            uint32_t k = kb[i];
            if ((k >> 19) >= piv) {
                uint32_t pos = atomicAdd(&s_pos, 1u);
                if (pos < CCAP) {
                    candKey[(size_t)b * CCAP + pos] = k;
                    candIdx[(size_t)b * CCAP + pos] = (uint32_t)i;
                }
            }
        }
        __syncthreads();
        if (tid == 0) candCount[b] = s_pos < CCAP ? s_pos : CCAP;
    }
    gg.sync();

    // ================= P3: exact rank (packed u64 desc) + decode (16 segs/image) =================
    {
        int b = bx >> 4, seg = bx & 15;
        int C = (int)candCount[b];
        const uint32_t* ck = candKey + (size_t)b * CCAP;
        const uint32_t* ci = candIdx + (size_t)b * CCAP;
        for (int j = tid; j < C; j += BLK)
            tp[j] = ((unsigned long long)ck[j] << 32) | (uint32_t)(~ci[j]);
        __syncthreads();
        int c = seg * BLK + tid;
        if (c < C) {
            unsigned long long mine = tp[c];
            uint32_t mk = (uint32_t)(mine >> 32);
            uint32_t mi = ~(uint32_t)mine;
            uint32_t r = 0;
#pragma unroll 4
            for (int j = 0; j < C; ++j) r += (tp[j] > mine);
            if (r < (uint32_t)KPRE) {
                uint32_t idx = mi;
                const float* an = anchors + (size_t)idx * 4;
                float a0 = an[0], a1 = an[1], a2 = an[2], a3 = an[3];
                const float* dp = boxp + ((size_t)b * AANCH + idx) * 4;
                float d0 = dp[0], d1 = dp[1], d2 = dp[2], d3 = dp[3];
                float aw = a2 - a0, ah = a3 - a1;
                float acx = a0 + 0.5f * aw, acy = a1 + 0.5f * ah;
                float cx = d0 * aw + acx, cy = d1 * ah + acy;
                float w = expf(d2) * aw, hh = expf(d3) * ah;
                float x1 = fminf(fmaxf(cx - 0.5f * w, 0.0f), 512.0f);
                float y1 = fminf(fmaxf(cy - 0.5f * hh, 0.0f), 512.0f);
                float x2 = fminf(fmaxf(cx + 0.5f * w, 0.0f), 512.0f);
                float y2 = fminf(fmaxf(cy + 0.5f * hh, 0.0f), 512.0f);
                float score;
                if (mk == 0u) {
                    score = -1.0f;
                } else {
                    uint32_t ub = (mk & 0x80000000u) ? (mk ^ 0x80000000u) : ~mk;
                    score = 1.0f / (1.0f + expf(-__uint_as_float(ub)));
                }
                int t = b * KPRE + (int)r;
                topBox[t] = make_float4(x1, y1, x2, y2);
                topScore[t] = score;
                topLabel[t] = label[(size_t)b * AANCH + idx];
            }
        }
    }
    gg.sync();

    // ================= P4: transposed suppression mask (2176 wave-jobs, blocks 0..135) =================
    if (bx < 136) {   // block-uniform: wv = bx*16+w < 2176 iff bx < 136
        int w = tid >> 6, lane = tid & 63;
        int wv = (bx << 4) | w;
        int b = wv / 136;
        int tt = wv - b * 136;
        int rb = 0;
        while (tt >= NCH - rb) { tt -= NCH - rb; ++rb; }
        int cb = rb + tt;
        int j = cb * 64 + lane;
        float4 vj;
        if (j < KPRE) {
            vj = topBox[b * KPRE + j];
            float off = (float)topLabel[b * KPRE + j] * 10000.0f;
            vj.x += off; vj.y += off; vj.z += off; vj.w += off;
        } else {
            vj = make_float4(-3e37f, -3e37f, -3e37f, -3e37f);
        }
        cobS[w][lane] = vj;
        carS[w][lane] = fmaxf(vj.z - vj.x, 0.0f) * fmaxf(vj.w - vj.y, 0.0f);
        int i2 = rb * 64 + lane;
        float4 bi2;
        if (i2 < KPRE) {
            bi2 = topBox[b * KPRE + i2];
            float off = (float)topLabel[b * KPRE + i2] * 10000.0f;
            bi2.x += off; bi2.y += off; bi2.z += off; bi2.w += off;
        } else {
            bi2 = make_float4(-3e37f, -3e37f, -3e37f, -3e37f);
        }
        float ai = fmaxf(bi2.z - bi2.x, 0.0f) * fmaxf(bi2.w - bi2.y, 0.0f);
        __syncthreads();
        unsigned long long myword = 0;
#pragma unroll 8
        for (int jj = 0; jj < 64; ++jj) {
            int jg = cb * 64 + jj;
            float4 bj = cobS[w][jj];
            float ltx = fmaxf(bi2.x, bj.x), lty = fmaxf(bi2.y, bj.y);
            float rbx = fminf(bi2.z, bj.z), rby = fminf(bi2.w, bj.w);
            float wx = fmaxf(rbx - ltx, 0.0f), wy = fmaxf(rby - lty, 0.0f);
            float inter = wx * wy;
            float iou = inter / fmaxf(ai + carS[w][jj] - inter, 1e-6f);
            bool pred = (iou > 0.5f) && (i2 < jg) && (i2 < KPRE) && (jg < KPRE);
            unsigned long long bal = __ballot(pred);  // bit<lane> = source i2 suppresses jg
            if (lane == jj) myword = bal;
        }
        maskT[(((size_t)b * NCH + rb) * NCH + cb) * 64 + lane] = myword;
    }
    gg.sync();

    // ================= P5: greedy NMS + output, 1 wave/image, register-only =================
    if (bx < NB && tid < 64) {
        int b = bx, lane = tid;
        int V = (int)validCnt[b];
        const unsigned long long* mtb = maskT + (size_t)b * NCH * NCH * 64;
        unsigned long long km[NCH];
#pragma unroll
        for (int s = 0; s < NCH; ++s) km[s] = 0ull;
        int count = 0;
        unsigned long long mt[NCH];
#pragma unroll
        for (int s = 0; s < NCH; ++s) mt[s] = mtb[((size_t)s * NCH + 0) * 64 + lane];
#pragma unroll
        for (int c = 0; c < NCH; ++c) {
            bool go = (c * 64 < V) && (count < MAXDET);
            unsigned long long cur[NCH];
#pragma unroll
            for (int s = 0; s < NCH; ++s) cur[s] = mt[s];
            if (go && c + 1 < NCH) {
#pragma unroll
                for (int s = 0; s < NCH; ++s) mt[s] = mtb[((size_t)s * NCH + (c + 1)) * 64 + lane];
            }
            unsigned long long kmask = 0;
            if (go) {
                unsigned long long dd = 0;
                unsigned long long colbits = cur[c];
#pragma unroll
                for (int s = 0; s < NCH; ++s) dd |= (cur[s] & km[s]);
                bool dead = dd != 0ull;
                bool valid = (c * 64 + lane) < V;
                bool kept = false;
                while (count < MAXDET) {
                    unsigned long long undec = __ballot((!dead) && (!kept) && valid);
                    if (undec == 0ull) break;
                    int f = __builtin_ctzll(undec);
                    kmask |= 1ull << f;
                    ++count;
                    if (lane == f) kept = true;
                    dead = dead || (((colbits >> f) & 1ull) != 0ull);
                }
            }
            km[c] = kmask;   // uniform across lanes
        }
        int pf[NCH + 1];
        pf[0] = 0;
#pragma unroll
        for (int cc = 0; cc < NCH; ++cc) pf[cc + 1] = pf[cc] + __popcll(km[cc]);
        int total = pf[NCH];
#pragma unroll
        for (int cc = 0; cc < NCH; ++cc) {
            unsigned long long m = km[cc];
            if ((m >> lane) & 1ull) {
                int slot = pf[cc] + __popcll(m & ((1ull << lane) - 1ull));
                int g = cc * 64 + lane;
                int tdx = b * MAXDET + slot;
                float4 box = topBox[b * KPRE + g];
                out[(size_t)tdx * 4 + 0] = box.x;
                out[(size_t)tdx * 4 + 1] = box.y;
                out[(size_t)tdx * 4 + 2] = box.z;
                out[(size_t)tdx * 4 + 3] = box.w;
                out[(size_t)NB * MAXDET * 4 + tdx] = topScore[b * KPRE + g];
                out[(size_t)NB * MAXDET * 5 + tdx] = (float)(topLabel[b * KPRE + g] + 1);
            }
        }
        for (int k2 = lane; k2 < MAXDET; k2 += 64) {
            if (k2 >= total) {
                int tdx = b * MAXDET + k2;
                out[(size_t)tdx * 4 + 0] = 0.0f;
                out[(size_t)tdx * 4 + 1] = 0.0f;
                out[(size_t)tdx * 4 + 2] = 0.0f;
                out[(size_t)tdx * 4 + 3] = 0.0f;
                out[(size_t)NB * MAXDET * 4 + tdx] = 0.0f;
                out[(size_t)NB * MAXDET * 5 + tdx] = 0.0f;
            }
        }
    }
}

extern "C" void kernel_launch(void* const* d_in, const int* in_sizes, int n_in,
                              void* d_out, int out_size, void* d_ws, size_t ws_size,
                              hipStream_t stream) {
    const float* cls = (const float*)d_in[0];
    const float* boxp = (const float*)d_in[1];
    const float* anchors = (const float*)d_in[2];
    float* out = (float*)d_out;

    char* wsp = (char*)d_ws;
    size_t off = 0;
    auto carve = [&](size_t bytes) -> void* {
        void* p = wsp + off;
        off += (bytes + 255) & ~(size_t)255;
        return p;
    };
    unsigned long long* maskT = (unsigned long long*)carve((size_t)NB * NCH * NCH * 64 * 8);
    uint32_t* key       = (uint32_t*)carve((size_t)NB * AANCH * 4);
    int*      label     = (int*)carve((size_t)NB * AANCH * 4);
    uint32_t* candKey   = (uint32_t*)carve((size_t)NB * CCAP * 4);
    uint32_t* candIdx   = (uint32_t*)carve((size_t)NB * CCAP * 4);
    float4*   topBox    = (float4*)carve((size_t)NB * KPRE * 16);
    float*    topScore  = (float*)carve((size_t)NB * KPRE * 4);
    int*      topLabel  = (int*)carve((size_t)NB * KPRE * 4);
    uint32_t* validCnt  = (uint32_t*)carve((size_t)NB * 4);
    uint32_t* candCount = (uint32_t*)carve((size_t)NB * 4);
    (void)ws_size; (void)out_size; (void)n_in; (void)in_sizes;

    void* args[] = {
        (void*)&cls, (void*)&boxp, (void*)&anchors, (void*)&out,
        (void*)&key, (void*)&label, (void*)&candKey, (void*)&candIdx,
        (void*)&candCount, (void*)&validCnt, (void*)&topBox, (void*)&topScore,
        (void*)&topLabel, (void*)&maskT
    };
    hipLaunchCooperativeKernel((void*)mega, dim3(GRID), dim3(BLK), args, 0, stream);
}